// Round 1
// baseline (364.499 us; speedup 1.0000x reference)
//
#include <hip/hip_runtime.h>
#include <math.h>

// ScaledDotProductAttention: causal + key-padding-mask attention.
// q,k,v: (N=64, T=1024, D=64) fp32. out: (64,1024,64) fp32.
// Flash-attention tiling: QT=64 query rows per block, KT=64 key tile in LDS.
// 256 threads: thread = (row r = tid>>2, d-quarter quad = tid&3).

#define N_HEADS 64
#define T_SEQ   1024
#define D_HEAD  64
#define QT      64
#define KT      64
#define PADDING_NUM (-4294967295.0f)   // -2^32 + 1

__global__ __launch_bounds__(256)
void attn_fwd(const float* __restrict__ q,
              const float* __restrict__ k,
              const float* __restrict__ v,
              float* __restrict__ out) {
    __shared__ float Ks[KT][D_HEAD];    // 16 KB
    __shared__ float Vs[KT][D_HEAD];    // 16 KB
    __shared__ float kvalid[KT];        // 256 B  (1.0 = valid key, 0.0 = padded)

    const int bx   = blockIdx.x;
    const int n    = bx & 63;          // head
    const int qt   = bx >> 6;          // query-tile index (0..15)
    const int tid  = threadIdx.x;
    const int r    = tid >> 2;         // query row in tile (0..63)
    const int quad = tid & 3;          // d-quarter (0..3)
    const int d0   = quad * 16;

    const int gi = qt * QT + r;        // global query row
    const float scale = 0.125f;        // 1/sqrt(64)

    // Q row quarter -> registers, pre-scaled
    float qreg[16];
    {
        const float* qptr = q + ((size_t)n * T_SEQ + gi) * D_HEAD + d0;
        #pragma unroll
        for (int x = 0; x < 4; ++x) {
            float4 t4 = *(const float4*)(qptr + x * 4);
            qreg[x*4+0] = t4.x * scale;
            qreg[x*4+1] = t4.y * scale;
            qreg[x*4+2] = t4.z * scale;
            qreg[x*4+3] = t4.w * scale;
        }
    }

    float o[16];
    #pragma unroll
    for (int x = 0; x < 16; ++x) o[x] = 0.f;
    float m = -INFINITY;
    float l = 0.f;

    const int ntiles = qt + 1;         // causal: only key tiles <= query tile
    for (int kt = 0; kt < ntiles; ++kt) {
        const int kbase = kt * KT;

        __syncthreads();               // protect LDS reuse across iterations
        {   // stage K,V tiles: 4096 floats each, coalesced float4
            const float4* kptr = (const float4*)(k + ((size_t)n * T_SEQ + kbase) * D_HEAD);
            const float4* vptr = (const float4*)(v + ((size_t)n * T_SEQ + kbase) * D_HEAD);
            float4* ks4 = (float4*)Ks;
            float4* vs4 = (float4*)Vs;
            #pragma unroll
            for (int x = 0; x < 4; ++x) {
                int idx = tid + x * 256;
                ks4[idx] = kptr[idx];
                vs4[idx] = vptr[idx];
            }
        }
        __syncthreads();

        // key-padding mask: sum(|k_row|) != 0
        if (tid < KT) {
            float s = 0.f;
            #pragma unroll 8
            for (int d = 0; d < D_HEAD; ++d) s += fabsf(Ks[tid][d]);
            kvalid[tid] = (s != 0.f) ? 1.f : 0.f;
        }
        __syncthreads();

        // ---- QK^T: partial dot over this thread's 16 dims, 4-lane reduce ----
        float p[KT];
        float tmax = -INFINITY;
        #pragma unroll
        for (int j = 0; j < KT; ++j) {
            const float4* krow = (const float4*)&Ks[j][d0];
            float4 a0 = krow[0], a1 = krow[1], a2 = krow[2], a3 = krow[3];
            float s;
            s  = qreg[0]  * a0.x; s += qreg[1]  * a0.y;
            s += qreg[2]  * a0.z; s += qreg[3]  * a0.w;
            s += qreg[4]  * a1.x; s += qreg[5]  * a1.y;
            s += qreg[6]  * a1.z; s += qreg[7]  * a1.w;
            s += qreg[8]  * a2.x; s += qreg[9]  * a2.y;
            s += qreg[10] * a2.z; s += qreg[11] * a2.w;
            s += qreg[12] * a3.x; s += qreg[13] * a3.y;
            s += qreg[14] * a3.z; s += qreg[15] * a3.w;
            // reduce across the 4 quarter-lanes (lanes r*4 .. r*4+3)
            s += __shfl_xor(s, 1);
            s += __shfl_xor(s, 2);
            // masks: key padding + causal. Exactly PADDING_NUM like the reference.
            bool ok = (kvalid[j] != 0.f) && (kbase + j <= gi);
            s = ok ? s : PADDING_NUM;
            p[j] = s;
            tmax = fmaxf(tmax, s);
        }

        // ---- online softmax update ----
        float newm = fmaxf(m, tmax);
        float corr = __expf(m - newm);   // first tile: exp(-inf)=0
        l *= corr;
        #pragma unroll
        for (int x = 0; x < 16; ++x) o[x] *= corr;

        float lsum = 0.f;
        #pragma unroll
        for (int j = 0; j < KT; ++j) {
            float pj = __expf(p[j] - newm);   // masked -> exp(~-4e9) -> 0
            p[j] = pj;
            lsum += pj;
        }
        l += lsum;
        m = newm;

        // ---- PV: o[d] += sum_j p[j] * V[j][d] ----
        #pragma unroll
        for (int j = 0; j < KT; ++j) {
            const float4* vrow = (const float4*)&Vs[j][d0];
            float4 b0 = vrow[0], b1 = vrow[1], b2 = vrow[2], b3 = vrow[3];
            float pj = p[j];
            o[0]  += pj * b0.x; o[1]  += pj * b0.y;
            o[2]  += pj * b0.z; o[3]  += pj * b0.w;
            o[4]  += pj * b1.x; o[5]  += pj * b1.y;
            o[6]  += pj * b1.z; o[7]  += pj * b1.w;
            o[8]  += pj * b2.x; o[9]  += pj * b2.y;
            o[10] += pj * b2.z; o[11] += pj * b2.w;
            o[12] += pj * b3.x; o[13] += pj * b3.y;
            o[14] += pj * b3.z; o[15] += pj * b3.w;
        }
    }

    // ---- epilogue ----
    float inv = 1.f / l;
    float* optr = out + ((size_t)n * T_SEQ + gi) * D_HEAD + d0;
    #pragma unroll
    for (int x = 0; x < 4; ++x) {
        float4 t4;
        t4.x = o[x*4+0] * inv;
        t4.y = o[x*4+1] * inv;
        t4.z = o[x*4+2] * inv;
        t4.w = o[x*4+3] * inv;
        *(float4*)(optr + x * 4) = t4;
    }
}

extern "C" void kernel_launch(void* const* d_in, const int* in_sizes, int n_in,
                              void* d_out, int out_size, void* d_ws, size_t ws_size,
                              hipStream_t stream) {
    const float* q = (const float*)d_in[0];
    const float* k = (const float*)d_in[1];
    const float* v = (const float*)d_in[2];
    float* out = (float*)d_out;

    // grid: n = bx & 63, qt = bx >> 6  (mixes heavy/light query tiles across CUs)
    dim3 grid(N_HEADS * (T_SEQ / QT));
    dim3 block(256);
    hipLaunchKernelGGL(attn_fwd, grid, block, 0, stream, q, k, v, out);
}

// Round 2
// 264.395 us; speedup vs baseline: 1.3786x; 1.3786x over previous
//
#include <hip/hip_runtime.h>
#include <math.h>

// Causal + key-padding-mask attention, fp32. (N=64, T=1024, D=64)
// Flash tiling: QT=64 query rows/block (256 thr: r=tid>>2, quad=tid&3),
// KT=32 key tile, double-buffered LDS staged via global_load_lds (async),
// key-padding mask computed from global as additive 0/PADDING_NUM, pipelined.

#define N_HEADS 64
#define T_SEQ   1024
#define D_HEAD  64
#define QT      64
#define KT      32
#define NQT     (T_SEQ / QT)              // 16
#define PADDING_NUM (-4294967295.0f)      // -2^32 + 1 (rounds to -2^32 in fp32, same as ref)

#define GLOAD_LDS16(gptr, ldsptr)                                              \
    __builtin_amdgcn_global_load_lds(                                          \
        (const __attribute__((address_space(1))) void*)(gptr),                 \
        (__attribute__((address_space(3))) void*)(ldsptr), 16, 0, 0)

template<bool B> struct BoolC { static constexpr bool value = B; };

__global__ __launch_bounds__(256)
void attn_fwd(const float* __restrict__ q,
              const float* __restrict__ k,
              const float* __restrict__ v,
              float* __restrict__ out) {
    __shared__ float Ks[2][KT][D_HEAD];   // 2 x 8 KB
    __shared__ float Vs[2][KT][D_HEAD];   // 2 x 8 KB
    __shared__ float Kadds[2][KT];        // additive key mask: 0.0 or PADDING_NUM

    const int bx   = blockIdx.x;
    const int n    = bx & 63;
    const int qt   = (NQT - 1) - (bx >> 6);   // heavy tiles first
    const int tid  = threadIdx.x;
    const int wave = tid >> 6;
    const int lane = tid & 63;
    const int r    = tid >> 2;           // query row in tile (0..63)
    const int quad = tid & 3;            // d-quarter
    const int d0   = quad * 16;
    const int gi      = qt * QT + r;     // global query row
    const int gi_wmin = qt * QT + wave * 16;   // wave's min/max query row
    const int gi_wmax = gi_wmin + 15;

    const float* kh = k + (size_t)n * T_SEQ * D_HEAD;
    const float* vh = v + (size_t)n * T_SEQ * D_HEAD;

    // Q quarter-row -> regs, pre-scaled by 1/sqrt(64)
    float qreg[16];
    {
        const float* qp = q + ((size_t)n * T_SEQ + gi) * D_HEAD + d0;
        #pragma unroll
        for (int x = 0; x < 4; ++x) {
            float4 t = ((const float4*)qp)[x];
            qreg[4*x+0] = t.x * 0.125f; qreg[4*x+1] = t.y * 0.125f;
            qreg[4*x+2] = t.z * 0.125f; qreg[4*x+3] = t.w * 0.125f;
        }
    }

    float o[16];
    #pragma unroll
    for (int x = 0; x < 16; ++x) o[x] = 0.f;
    float m = -INFINITY, l = 0.f;

    // ---- async staging: tile -> LDS buffer b (wave-chunked, linear dest) ----
    auto stage = [&](int t, int b) {
        const float* kg = kh + (size_t)t * KT * D_HEAD;
        const float* vg = vh + (size_t)t * KT * D_HEAD;
        float* kd = &Ks[b][0][0];
        float* vd = &Vs[b][0][0];
        #pragma unroll
        for (int h = 0; h < 2; ++h) {
            const int c = wave + h * 4;               // 1 KB chunk id (0..7)
            GLOAD_LDS16(kg + c * 256 + lane * 4, kd + c * 256);
            GLOAD_LDS16(vg + c * 256 + lane * 4, vd + c * 256);
        }
    };

    // ---- key-padding mask, pipelined: issue loads early, reduce late ----
    const int jr  = tid >> 3;            // key row 0..31
    const int oct = tid & 7;             // 8 floats per lane
    float4 ka4, kb4;
    auto kadd_load = [&](int t) {        // coalesced global read of K tile
        const float* kr = kh + (size_t)t * KT * D_HEAD + jr * D_HEAD + oct * 8;
        ka4 = ((const float4*)kr)[0];
        kb4 = ((const float4*)kr)[1];
    };
    auto kadd_finish = [&](int b) {
        float s = fabsf(ka4.x) + fabsf(ka4.y) + fabsf(ka4.z) + fabsf(ka4.w)
                + fabsf(kb4.x) + fabsf(kb4.y) + fabsf(kb4.z) + fabsf(kb4.w);
        s += __shfl_xor(s, 1); s += __shfl_xor(s, 2); s += __shfl_xor(s, 4);
        if (oct == 0) Kadds[b][jr] = (s != 0.f) ? 0.f : PADDING_NUM;
    };

    // ---- one KT-tile of flash attention ----
    auto process = [&](int b, int kbase, auto causal_c) {
        constexpr bool CAUSAL = decltype(causal_c)::value;
        const int lim = gi - kbase;
        float p[KT];
        float tmax = -INFINITY;
        #pragma unroll
        for (int j = 0; j < KT; ++j) {
            const float4* kr4 = (const float4*)&Ks[b][j][d0];   // broadcast reads
            float4 a0 = kr4[0], a1 = kr4[1], a2 = kr4[2], a3 = kr4[3];
            float s0 = qreg[0] * a0.x;
            s0 = fmaf(qreg[1],  a0.y, s0); s0 = fmaf(qreg[2],  a0.z, s0); s0 = fmaf(qreg[3],  a0.w, s0);
            float s1 = qreg[4] * a1.x;
            s1 = fmaf(qreg[5],  a1.y, s1); s1 = fmaf(qreg[6],  a1.z, s1); s1 = fmaf(qreg[7],  a1.w, s1);
            float s2 = qreg[8] * a2.x;
            s2 = fmaf(qreg[9],  a2.y, s2); s2 = fmaf(qreg[10], a2.z, s2); s2 = fmaf(qreg[11], a2.w, s2);
            float s3 = qreg[12] * a3.x;
            s3 = fmaf(qreg[13], a3.y, s3); s3 = fmaf(qreg[14], a3.z, s3); s3 = fmaf(qreg[15], a3.w, s3);
            float s = (s0 + s1) + (s2 + s3);
            s += __shfl_xor(s, 1);        // reduce across the 4 quarter-lanes
            s += __shfl_xor(s, 2);
            s += Kadds[b][j];             // additive key-padding mask (0 or PAD)
            if (CAUSAL) s = (j <= lim) ? s : PADDING_NUM;
            p[j] = s;
            tmax = fmaxf(tmax, s);
        }
        const float newm = fmaxf(m, tmax);
        const float corr = __expf(m - newm);
        l *= corr;
        #pragma unroll
        for (int x = 0; x < 16; ++x) o[x] *= corr;
        float ls = 0.f;
        #pragma unroll
        for (int j = 0; j < KT; ++j) {
            const float pj = __expf(p[j] - newm);   // masked -> 0
            p[j] = pj;
            ls += pj;
        }
        l += ls; m = newm;
        #pragma unroll
        for (int j = 0; j < KT; ++j) {
            const float4* vr4 = (const float4*)&Vs[b][j][d0];   // broadcast reads
            float4 b0 = vr4[0], b1 = vr4[1], b2 = vr4[2], b3 = vr4[3];
            const float pj = p[j];
            o[0]  = fmaf(pj, b0.x, o[0]);  o[1]  = fmaf(pj, b0.y, o[1]);
            o[2]  = fmaf(pj, b0.z, o[2]);  o[3]  = fmaf(pj, b0.w, o[3]);
            o[4]  = fmaf(pj, b1.x, o[4]);  o[5]  = fmaf(pj, b1.y, o[5]);
            o[6]  = fmaf(pj, b1.z, o[6]);  o[7]  = fmaf(pj, b1.w, o[7]);
            o[8]  = fmaf(pj, b2.x, o[8]);  o[9]  = fmaf(pj, b2.y, o[9]);
            o[10] = fmaf(pj, b2.z, o[10]); o[11] = fmaf(pj, b2.w, o[11]);
            o[12] = fmaf(pj, b3.x, o[12]); o[13] = fmaf(pj, b3.y, o[13]);
            o[14] = fmaf(pj, b3.z, o[14]); o[15] = fmaf(pj, b3.w, o[15]);
        }
    };

    // ---- prologue: tile 0 ----
    kadd_load(0);        // vector loads first (so waiting on them never drains
    stage(0, 0);         // the newer global_load_lds queue)
    kadd_finish(0);
    __syncthreads();

    const int ntiles = 2 * qt + 2;
    int buf = 0;
    for (int t = 0; t < ntiles; ++t) {
        const int kbase = t * KT;
        const bool haveNext = (t + 1 < ntiles);
        if (haveNext) {                    // issue next tile (loads in flight
            kadd_load(t + 1);              //  across the whole compute phase)
            stage(t + 1, buf ^ 1);
        }
        if (kbase <= gi_wmax) {            // wave-uniform: skip fully-masked tiles
            if (kbase + KT - 1 <= gi_wmin) process(buf, kbase, BoolC<false>{});
            else                           process(buf, kbase, BoolC<true>{});
        }
        if (haveNext) kadd_finish(buf ^ 1);
        __syncthreads();                   // drains vmcnt: next buffer ready
        buf ^= 1;
    }

    // ---- epilogue ----
    const float inv = 1.f / l;
    float* op = out + ((size_t)n * T_SEQ + gi) * D_HEAD + d0;
    #pragma unroll
    for (int x = 0; x < 4; ++x) {
        float4 t4;
        t4.x = o[4*x+0] * inv; t4.y = o[4*x+1] * inv;
        t4.z = o[4*x+2] * inv; t4.w = o[4*x+3] * inv;
        ((float4*)op)[x] = t4;
    }
}

extern "C" void kernel_launch(void* const* d_in, const int* in_sizes, int n_in,
                              void* d_out, int out_size, void* d_ws, size_t ws_size,
                              hipStream_t stream) {
    (void)d_ws; (void)ws_size; (void)in_sizes; (void)n_in; (void)out_size;
    const float* q = (const float*)d_in[0];
    const float* k = (const float*)d_in[1];
    const float* v = (const float*)d_in[2];
    float* o = (float*)d_out;
    dim3 grid(N_HEADS * NQT);
    dim3 block(256);
    hipLaunchKernelGGL(attn_fwd, grid, block, 0, stream, q, k, v, o);
}

// Round 3
// 49.151 us; speedup vs baseline: 7.4159x; 5.3792x over previous
//
#include <hip/hip_runtime.h>
#include <math.h>

// Causal + key-padding-mask attention, MFMA bf16 path. (N=64, T=1024, D=64)
// Structure (per guide §B attn):
//  - block = 256 thr = 4 waves; wave owns 32 q-rows (QBLK=128/block); grid = 64 heads x 8.
//  - KVB=64 key tile; K staged [key][dim] bf16, V staged TRANSPOSED [dim][key] bf16,
//    both with 144B row stride (odd 16B-granule count -> bank spread, b128-aligned).
//  - QK^T swapped: S^T = mfma(A=K, B=Q^T) -> D[key][q]: lane = q (col), scores lane-local.
//  - PV swapped:   O^T = mfma(A=V^T, B=P^T) -> D[d][q]: lane = q (col) -> m/l/corr lane-local.
//  - P^T B-frag built from exp'd scores via bf16 pack + half-wave swap (shfl_xor 32).
//  - fp32->bf16 conversion at staging (reg-staged, global_load_lds can't convert).
//  - masks: additive key-padding (0/PAD) + causal cndmask on diagonal tiles only.

#define N_HEADS 64
#define T_SEQ   1024
#define D_HEAD  64
#define QBLK    128
#define KVB     64
#define NQB     (T_SEQ / QBLK)            // 8
#define PADDING_NUM (-4294967295.0f)      // -2^32 + 1
#define KSTRIDE 144                       // 64 bf16 = 128B data + 16B pad (odd granules)
#define VSTRIDE 144

typedef __attribute__((ext_vector_type(8)))  short bf16x8;   // 4 VGPRs: MFMA A/B frag
typedef __attribute__((ext_vector_type(16))) float f32x16;   // 16 VGPRs: MFMA C/D
typedef __attribute__((ext_vector_type(4)))  unsigned int uint4v;

union FragU { uint4v u; bf16x8 v; };

template<bool B> struct BoolC { static constexpr bool value = B; };

static __device__ __forceinline__ unsigned f2bf(float f) {   // fp32 -> bf16 bits (RNE)
    union { float f; unsigned u; } c; c.f = f;
    return (c.u + 0x7fffu + ((c.u >> 16) & 1u)) >> 16;
}
static __device__ __forceinline__ unsigned pk2(float lo, float hi) {
    return f2bf(lo) | (f2bf(hi) << 16);
}
static __device__ __forceinline__ f32x16 zero16() {
    f32x16 z;
    #pragma unroll
    for (int i = 0; i < 16; ++i) z[i] = 0.f;
    return z;
}

__global__ __launch_bounds__(256)
void attn_fwd(const float* __restrict__ q, const float* __restrict__ k,
              const float* __restrict__ v, float* __restrict__ out) {
    __shared__ __align__(16) char  KT_lds[2][KVB * KSTRIDE];     // K tile, bf16 [key][dim]
    __shared__ __align__(16) char  VT_lds[2][D_HEAD * VSTRIDE];  // V^T tile, bf16 [dim][key]
    __shared__ __align__(16) float kadd[2][KVB];                 // additive pad mask

    const int bx  = blockIdx.x;
    const int n   = bx & 63;
    const int qb  = (NQB - 1) - (bx >> 6);   // heavy q-strips first
    const int tid = threadIdx.x;
    const int w   = tid >> 6;                // wave 0..3
    const int l   = tid & 63;
    const int h   = l >> 5;                  // half-wave
    const int ql  = l & 31;                  // this lane's q-row (within wave's 32)
    const int qrow = qb * QBLK + w * 32 + ql;

    const float* qg = q + (size_t)n * T_SEQ * D_HEAD;
    const float* kg = k + (size_t)n * T_SEQ * D_HEAD;
    const float* vg = v + (size_t)n * T_SEQ * D_HEAD;

    // ---- Q^T B-frags (once): lane supplies Q[q=ql][dim = s*16 + h*8 + e], pre-scaled ----
    FragU qf[4];
    #pragma unroll
    for (int s = 0; s < 4; ++s) {
        const float* qp = qg + (size_t)qrow * D_HEAD + s * 16 + h * 8;
        float4 a = ((const float4*)qp)[0], b = ((const float4*)qp)[1];
        qf[s].u[0] = pk2(a.x * 0.125f, a.y * 0.125f);
        qf[s].u[1] = pk2(a.z * 0.125f, a.w * 0.125f);
        qf[s].u[2] = pk2(b.x * 0.125f, b.y * 0.125f);
        qf[s].u[3] = pk2(b.z * 0.125f, b.w * 0.125f);
    }

    f32x16 O0 = zero16(), O1 = zero16();   // O^T acc: d = crow+32g (rows), q = lane (col)
    float m = -INFINITY, l_sum = 0.f;

    // ---- staging registers (held across compute for issue-early overlap) ----
    float4 kbuf[2][2], vbuf[2][2];

    auto k_issue = [&](int t) {            // K: cell c -> (key=c>>3, oct=c&7), coalesced
        const float* base = kg + (size_t)t * KVB * D_HEAD;
        #pragma unroll
        for (int i = 0; i < 2; ++i) {
            int c = tid + 256 * i; int key = c >> 3, oct = c & 7;
            const float4* p = (const float4*)(base + key * D_HEAD + oct * 8);
            kbuf[i][0] = p[0]; kbuf[i][1] = p[1];
        }
    };
    auto v_issue = [&](int t) {            // V: cell c -> (kp=c&31, dq=c>>5), 2 key rows
        const float* base = vg + (size_t)t * KVB * D_HEAD;
        #pragma unroll
        for (int i = 0; i < 2; ++i) {
            int c = tid + 256 * i; int kp = c & 31, dq = c >> 5;
            const float* p0 = base + (2 * kp) * D_HEAD + dq * 4;
            vbuf[i][0] = *(const float4*)p0;
            vbuf[i][1] = *(const float4*)(p0 + D_HEAD);
        }
    };
    auto kv_write = [&](int b) {           // cvt fp32->bf16, write K + V^T + kadd
        #pragma unroll
        for (int i = 0; i < 2; ++i) {
            int c = tid + 256 * i; int key = c >> 3, oct = c & 7;
            float4 A = kbuf[i][0], B = kbuf[i][1];
            float s = fabsf(A.x) + fabsf(A.y) + fabsf(A.z) + fabsf(A.w)
                    + fabsf(B.x) + fabsf(B.y) + fabsf(B.z) + fabsf(B.w);
            s += __shfl_xor(s, 1); s += __shfl_xor(s, 2); s += __shfl_xor(s, 4);
            if (oct == 0) kadd[b][key] = (s != 0.f) ? 0.f : PADDING_NUM;
            uint4v w4;
            w4[0] = pk2(A.x, A.y); w4[1] = pk2(A.z, A.w);
            w4[2] = pk2(B.x, B.y); w4[3] = pk2(B.z, B.w);
            *(uint4v*)(KT_lds[b] + key * KSTRIDE + oct * 16) = w4;

            int kp = c & 31, dq = c >> 5;
            float4 VA = vbuf[i][0], VB = vbuf[i][1];   // keys 2kp, 2kp+1; dims dq*4..+3
            *(unsigned*)(VT_lds[b] + (dq * 4 + 0) * VSTRIDE + kp * 4) = pk2(VA.x, VB.x);
            *(unsigned*)(VT_lds[b] + (dq * 4 + 1) * VSTRIDE + kp * 4) = pk2(VA.y, VB.y);
            *(unsigned*)(VT_lds[b] + (dq * 4 + 2) * VSTRIDE + kp * 4) = pk2(VA.z, VB.z);
            *(unsigned*)(VT_lds[b] + (dq * 4 + 3) * VSTRIDE + kp * 4) = pk2(VA.w, VB.w);
        }
    };

    // ---- one 64-key tile ----
    auto process = [&](int b, int t, auto causal_c) {
        constexpr bool CAUSAL = decltype(causal_c)::value;
        const char* Kb = KT_lds[b];
        const char* Vb = VT_lds[b];

        // QK^T swapped: S^T[key][q] ; lane holds q=ql, keys crow(r,h)+32*kgi
        f32x16 S[2];
        #pragma unroll
        for (int kgi = 0; kgi < 2; ++kgi) {
            f32x16 acc = zero16();
            #pragma unroll
            for (int s = 0; s < 4; ++s) {
                bf16x8 kf = *(const bf16x8*)(Kb + (kgi * 32 + ql) * KSTRIDE + s * 32 + h * 16);
                acc = __builtin_amdgcn_mfma_f32_32x32x16_bf16(kf, qf[s].v, acc, 0, 0, 0);
            }
            S[kgi] = acc;
        }

        // masks (additive pad + causal) + row max; reg r -> key crow = (r&3)+8*(r>>2)+4h
        float tmax = -INFINITY;
        #pragma unroll
        for (int kgi = 0; kgi < 2; ++kgi) {
            #pragma unroll
            for (int rq = 0; rq < 4; ++rq) {
                float4 kd = *(const float4*)&kadd[b][kgi * 32 + rq * 8 + 4 * h];
                #pragma unroll
                for (int j = 0; j < 4; ++j) {
                    int r = rq * 4 + j;
                    float sc = S[kgi][r] + ((const float*)&kd)[j];
                    if (CAUSAL) {
                        int key = t * KVB + kgi * 32 + rq * 8 + 4 * h + j;
                        sc = (key <= qrow) ? sc : PADDING_NUM;
                    }
                    S[kgi][r] = sc;
                    tmax = fmaxf(tmax, sc);
                }
            }
        }
        tmax = fmaxf(tmax, __shfl_xor(tmax, 32));   // combine lane-pair halves

        const float newm = fmaxf(m, tmax);
        const float corr = __expf(m - newm);        // first tile: exp(-inf)=0
        m = newm;
        l_sum *= corr;
        #pragma unroll
        for (int i = 0; i < 16; ++i) { O0[i] *= corr; O1[i] *= corr; }

        float ls = 0.f;
        #pragma unroll
        for (int kgi = 0; kgi < 2; ++kgi)
            #pragma unroll
            for (int r = 0; r < 16; ++r) {
                float p = __expf(S[kgi][r] - newm);   // masked -> 0
                S[kgi][r] = p;
                ls += p;
            }
        ls += __shfl_xor(ls, 32);
        l_sum += ls;

        // PV swapped: O^T += mfma(A=V^T, B=P^T). Build P^T frag: pack + half swap.
        #pragma unroll
        for (int kgi = 0; kgi < 2; ++kgi) {
            #pragma unroll
            for (int s2 = 0; s2 < 2; ++s2) {
                unsigned A0 = pk2(S[kgi][8 * s2 + 0], S[kgi][8 * s2 + 1]);
                unsigned A1 = pk2(S[kgi][8 * s2 + 2], S[kgi][8 * s2 + 3]);
                unsigned A2 = pk2(S[kgi][8 * s2 + 4], S[kgi][8 * s2 + 5]);
                unsigned A3 = pk2(S[kgi][8 * s2 + 6], S[kgi][8 * s2 + 7]);
                unsigned sw0 = (unsigned)__shfl_xor((int)A0, 32);
                unsigned sw1 = (unsigned)__shfl_xor((int)A1, 32);
                unsigned sw2 = (unsigned)__shfl_xor((int)A2, 32);
                unsigned sw3 = (unsigned)__shfl_xor((int)A3, 32);
                FragU pb;
                pb.u[0] = h ? sw2 : A0;   // elems 0,1: keys 16s2+ h*8 +0,1
                pb.u[1] = h ? sw3 : A1;   // elems 2,3
                pb.u[2] = h ? A2 : sw0;   // elems 4,5
                pb.u[3] = h ? A3 : sw1;   // elems 6,7
                const int ksf = kgi * 2 + s2;   // 16-key k-step within the 64-key tile
                bf16x8 vf0 = *(const bf16x8*)(Vb + (0 * 32 + ql) * VSTRIDE + ksf * 32 + h * 16);
                bf16x8 vf1 = *(const bf16x8*)(Vb + (1 * 32 + ql) * VSTRIDE + ksf * 32 + h * 16);
                O0 = __builtin_amdgcn_mfma_f32_32x32x16_bf16(vf0, pb.v, O0, 0, 0, 0);
                O1 = __builtin_amdgcn_mfma_f32_32x32x16_bf16(vf1, pb.v, O1, 0, 0, 0);
            }
        }
    };

    // ---- prologue: stage tile 0 ----
    k_issue(0); v_issue(0);
    kv_write(0);
    __syncthreads();

    const int nt    = 2 * (qb + 1);
    const int tdiag = 2 * qb + (w >> 1);   // wave's diagonal tile
    int buf = 0;
    for (int t = 0; t < nt; ++t) {
        if (t + 1 < nt) { k_issue(t + 1); v_issue(t + 1); }   // loads fly over compute
        if (t < tdiag)       process(buf, t, BoolC<false>{});
        else if (t == tdiag) process(buf, t, BoolC<true>{});
        if (t + 1 < nt) kv_write(buf ^ 1);
        __syncthreads();
        buf ^= 1;
    }

    // ---- epilogue: O^T rows are d=crow+32g, col q = lane (lane-local l_sum) ----
    const float inv = 1.f / l_sum;
    #pragma unroll
    for (int g = 0; g < 2; ++g) {
        #pragma unroll
        for (int r = 0; r < 16; ++r) {
            int d = (r & 3) + 8 * (r >> 2) + 4 * h + 32 * g;
            float val = (g ? O1[r] : O0[r]) * inv;
            out[(size_t)n * T_SEQ * D_HEAD + (size_t)qrow * D_HEAD + d] = val;
        }
    }
}

extern "C" void kernel_launch(void* const* d_in, const int* in_sizes, int n_in,
                              void* d_out, int out_size, void* d_ws, size_t ws_size,
                              hipStream_t stream) {
    (void)d_ws; (void)ws_size; (void)in_sizes; (void)n_in; (void)out_size;
    const float* q = (const float*)d_in[0];
    const float* k = (const float*)d_in[1];
    const float* v = (const float*)d_in[2];
    float* o = (float*)d_out;
    dim3 grid(N_HEADS * NQB);   // 512 blocks: n = bx&63, q-strip = 7-(bx>>6)
    dim3 block(256);
    hipLaunchKernelGGL(attn_fwd, grid, block, 0, stream, q, k, v, o);
}

// Round 4
// 46.707 us; speedup vs baseline: 7.8040x; 1.0523x over previous
//
#include <hip/hip_runtime.h>
#include <hip/hip_bf16.h>
#include <math.h>

// Causal + key-padding-mask attention, MFMA bf16 path. (N=64, T=1024, D=64)
//  - block = 256 thr = 4 waves. Block (n, pr) owns TWO 64-row half-strips of head n:
//    hs = 15-pr (heavy, 2 waves) and hs = pr (light, 2 waves) -> near-constant work
//    per block, no load-imbalance tail. Wave->member by parity, flipped by bx&1.
//  - KVB=64 key tile; K staged [key][dim] bf16, V staged TRANSPOSED [dim][key] bf16,
//    144B row stride (odd 16B granules -> bank spread, b128-aligned).
//  - QK^T swapped: S^T = mfma(A=K, B=Q^T) -> lane = q col; scores lane-local.
//  - PV swapped:   O^T = mfma(A=V^T, B=P^T) -> lane = q col; m/l/corr lane-local.
//  - softmax in exp2 domain (log2e folded into Q scale); v_cvt_pk_bf16_f32 packing.

#define N_HEADS 64
#define T_SEQ   1024
#define D_HEAD  64
#define KVB     64
#define PADDING_NUM (-4294967295.0f)      // -2^32 + 1
#define KSTRIDE 144
#define VSTRIDE 144
#define QSCALE  (0.125f * 1.4426950408889634f)   // 1/sqrt(64) * log2(e)

typedef __attribute__((ext_vector_type(8)))  short bf16x8;   // MFMA A/B frag
typedef __attribute__((ext_vector_type(16))) float f32x16;   // MFMA C/D
typedef __attribute__((ext_vector_type(4)))  unsigned int uint4v;

union FragU { uint4v u; bf16x8 v; };

template<bool B> struct BoolC { static constexpr bool value = B; };

static __device__ __forceinline__ unsigned pk2(float lo, float hi) {   // v_cvt_pk_bf16_f32
    union { __hip_bfloat162 h2; unsigned u; } c;
    c.h2 = __float22bfloat162_rn(make_float2(lo, hi));
    return c.u;
}
static __device__ __forceinline__ f32x16 zero16() {
    f32x16 z;
    #pragma unroll
    for (int i = 0; i < 16; ++i) z[i] = 0.f;
    return z;
}

__global__ __launch_bounds__(256)
void attn_fwd(const float* __restrict__ q, const float* __restrict__ k,
              const float* __restrict__ v, float* __restrict__ out) {
    __shared__ __align__(16) char  KT_lds[2][KVB * KSTRIDE];
    __shared__ __align__(16) char  VT_lds[2][D_HEAD * VSTRIDE];
    __shared__ __align__(16) float kadd[2][KVB];

    const int bx  = blockIdx.x;
    const int n   = bx & 63;
    const int pr  = bx >> 6;                 // pair id 0..7
    const int tid = threadIdx.x;
    const int w   = tid >> 6;
    const int l   = tid & 63;
    const int h   = l >> 5;
    const int ql  = l & 31;
    // wave -> half-strip: parity-interleaved heavy(15-pr)/light(pr) members
    const int sel  = (w ^ bx) & 1;           // 0 = heavy member, 1 = light member
    const int hs   = sel ? pr : (15 - pr);   // half-strip id 0..15 (64 rows each)
    const int qrow = hs * 64 + (w >> 1) * 32 + ql;

    const float* qg = q + (size_t)n * T_SEQ * D_HEAD;
    const float* kg = k + (size_t)n * T_SEQ * D_HEAD;
    const float* vg = v + (size_t)n * T_SEQ * D_HEAD;

    // ---- Q^T B-frags: lane = q col (ql), dims s*16 + h*8 + e, scaled to exp2 domain ----
    FragU qf[4];
    #pragma unroll
    for (int s = 0; s < 4; ++s) {
        const float* qp = qg + (size_t)qrow * D_HEAD + s * 16 + h * 8;
        float4 a = ((const float4*)qp)[0], b = ((const float4*)qp)[1];
        qf[s].u[0] = pk2(a.x * QSCALE, a.y * QSCALE);
        qf[s].u[1] = pk2(a.z * QSCALE, a.w * QSCALE);
        qf[s].u[2] = pk2(b.x * QSCALE, b.y * QSCALE);
        qf[s].u[3] = pk2(b.z * QSCALE, b.w * QSCALE);
    }

    f32x16 O0 = zero16(), O1 = zero16();
    float m = -INFINITY, l_sum = 0.f;

    float4 kbuf[2][2], vbuf[2][2];
    auto k_issue = [&](int t) {
        const float* base = kg + (size_t)t * KVB * D_HEAD;
        #pragma unroll
        for (int i = 0; i < 2; ++i) {
            int c = tid + 256 * i; int key = c >> 3, oct = c & 7;
            const float4* p = (const float4*)(base + key * D_HEAD + oct * 8);
            kbuf[i][0] = p[0]; kbuf[i][1] = p[1];
        }
    };
    auto v_issue = [&](int t) {
        const float* base = vg + (size_t)t * KVB * D_HEAD;
        #pragma unroll
        for (int i = 0; i < 2; ++i) {
            int c = tid + 256 * i; int kp = c & 31, dq = c >> 5;
            const float* p0 = base + (2 * kp) * D_HEAD + dq * 4;
            vbuf[i][0] = *(const float4*)p0;
            vbuf[i][1] = *(const float4*)(p0 + D_HEAD);
        }
    };
    auto kv_write = [&](int b) {
        #pragma unroll
        for (int i = 0; i < 2; ++i) {
            int c = tid + 256 * i; int key = c >> 3, oct = c & 7;
            float4 A = kbuf[i][0], B = kbuf[i][1];
            float s = fabsf(A.x) + fabsf(A.y) + fabsf(A.z) + fabsf(A.w)
                    + fabsf(B.x) + fabsf(B.y) + fabsf(B.z) + fabsf(B.w);
            s += __shfl_xor(s, 1); s += __shfl_xor(s, 2); s += __shfl_xor(s, 4);
            if (oct == 0) kadd[b][key] = (s != 0.f) ? 0.f : PADDING_NUM;
            uint4v w4;
            w4[0] = pk2(A.x, A.y); w4[1] = pk2(A.z, A.w);
            w4[2] = pk2(B.x, B.y); w4[3] = pk2(B.z, B.w);
            *(uint4v*)(KT_lds[b] + key * KSTRIDE + oct * 16) = w4;

            int kp = c & 31, dq = c >> 5;
            float4 VA = vbuf[i][0], VB = vbuf[i][1];
            *(unsigned*)(VT_lds[b] + (dq * 4 + 0) * VSTRIDE + kp * 4) = pk2(VA.x, VB.x);
            *(unsigned*)(VT_lds[b] + (dq * 4 + 1) * VSTRIDE + kp * 4) = pk2(VA.y, VB.y);
            *(unsigned*)(VT_lds[b] + (dq * 4 + 2) * VSTRIDE + kp * 4) = pk2(VA.z, VB.z);
            *(unsigned*)(VT_lds[b] + (dq * 4 + 3) * VSTRIDE + kp * 4) = pk2(VA.w, VB.w);
        }
    };

    auto process = [&](int b, int t, auto causal_c) {
        constexpr bool CAUSAL = decltype(causal_c)::value;
        const char* Kb = KT_lds[b];
        const char* Vb = VT_lds[b];

        f32x16 S[2];
        #pragma unroll
        for (int kgi = 0; kgi < 2; ++kgi) {
            f32x16 acc = zero16();
            #pragma unroll
            for (int s = 0; s < 4; ++s) {
                bf16x8 kf = *(const bf16x8*)(Kb + (kgi * 32 + ql) * KSTRIDE + s * 32 + h * 16);
                acc = __builtin_amdgcn_mfma_f32_32x32x16_bf16(kf, qf[s].v, acc, 0, 0, 0);
            }
            S[kgi] = acc;
        }

        float tmax = -INFINITY;
        #pragma unroll
        for (int kgi = 0; kgi < 2; ++kgi) {
            #pragma unroll
            for (int rq = 0; rq < 4; ++rq) {
                float4 kd = *(const float4*)&kadd[b][kgi * 32 + rq * 8 + 4 * h];
                #pragma unroll
                for (int j = 0; j < 4; ++j) {
                    int r = rq * 4 + j;
                    float sc = S[kgi][r] + ((const float*)&kd)[j];
                    if (CAUSAL) {
                        int key = t * KVB + kgi * 32 + rq * 8 + 4 * h + j;
                        sc = (key <= qrow) ? sc : PADDING_NUM;
                    }
                    S[kgi][r] = sc;
                    tmax = fmaxf(tmax, sc);
                }
            }
        }
        tmax = fmaxf(tmax, __shfl_xor(tmax, 32));

        const float newm = fmaxf(m, tmax);
        const float corr = __builtin_amdgcn_exp2f(m - newm);   // exp2 domain
        m = newm;
        l_sum *= corr;
        #pragma unroll
        for (int i = 0; i < 16; ++i) { O0[i] *= corr; O1[i] *= corr; }

        float ls = 0.f;
        #pragma unroll
        for (int kgi = 0; kgi < 2; ++kgi)
            #pragma unroll
            for (int r = 0; r < 16; ++r) {
                float p = __builtin_amdgcn_exp2f(S[kgi][r] - newm);
                S[kgi][r] = p;
                ls += p;
            }
        ls += __shfl_xor(ls, 32);
        l_sum += ls;

        #pragma unroll
        for (int kgi = 0; kgi < 2; ++kgi) {
            #pragma unroll
            for (int s2 = 0; s2 < 2; ++s2) {
                unsigned A0 = pk2(S[kgi][8 * s2 + 0], S[kgi][8 * s2 + 1]);
                unsigned A1 = pk2(S[kgi][8 * s2 + 2], S[kgi][8 * s2 + 3]);
                unsigned A2 = pk2(S[kgi][8 * s2 + 4], S[kgi][8 * s2 + 5]);
                unsigned A3 = pk2(S[kgi][8 * s2 + 6], S[kgi][8 * s2 + 7]);
                unsigned sw0 = (unsigned)__shfl_xor((int)A0, 32);
                unsigned sw1 = (unsigned)__shfl_xor((int)A1, 32);
                unsigned sw2 = (unsigned)__shfl_xor((int)A2, 32);
                unsigned sw3 = (unsigned)__shfl_xor((int)A3, 32);
                FragU pb;
                pb.u[0] = h ? sw2 : A0;
                pb.u[1] = h ? sw3 : A1;
                pb.u[2] = h ? A2 : sw0;
                pb.u[3] = h ? A3 : sw1;
                const int ksf = kgi * 2 + s2;
                bf16x8 vf0 = *(const bf16x8*)(Vb + (0 * 32 + ql) * VSTRIDE + ksf * 32 + h * 16);
                bf16x8 vf1 = *(const bf16x8*)(Vb + (1 * 32 + ql) * VSTRIDE + ksf * 32 + h * 16);
                O0 = __builtin_amdgcn_mfma_f32_32x32x16_bf16(vf0, pb.v, O0, 0, 0, 0);
                O1 = __builtin_amdgcn_mfma_f32_32x32x16_bf16(vf1, pb.v, O1, 0, 0, 0);
            }
        }
    };

    // ---- prologue ----
    k_issue(0); v_issue(0);
    kv_write(0);
    __syncthreads();

    const int nt = 16 - pr;                 // tiles needed by the heavy member
    int buf = 0;
    for (int t = 0; t < nt; ++t) {
        if (t + 1 < nt) { k_issue(t + 1); v_issue(t + 1); }
        if (t < hs)       process(buf, t, BoolC<false>{});   // wave-uniform branch
        else if (t == hs) process(buf, t, BoolC<true>{});
        if (t + 1 < nt) kv_write(buf ^ 1);
        __syncthreads();
        buf ^= 1;
    }

    // ---- epilogue: lane-local l_sum; O^T rows d = crow + 32g ----
    const float inv = 1.f / l_sum;
    #pragma unroll
    for (int g = 0; g < 2; ++g) {
        #pragma unroll
        for (int r = 0; r < 16; ++r) {
            int d = (r & 3) + 8 * (r >> 2) + 4 * h + 32 * g;
            float val = (g ? O1[r] : O0[r]) * inv;
            out[(size_t)n * T_SEQ * D_HEAD + (size_t)qrow * D_HEAD + d] = val;
        }
    }
}

extern "C" void kernel_launch(void* const* d_in, const int* in_sizes, int n_in,
                              void* d_out, int out_size, void* d_ws, size_t ws_size,
                              hipStream_t stream) {
    (void)d_ws; (void)ws_size; (void)in_sizes; (void)n_in; (void)out_size;
    const float* q = (const float*)d_in[0];
    const float* k = (const float*)d_in[1];
    const float* v = (const float*)d_in[2];
    float* o = (float*)d_out;
    dim3 grid(N_HEADS * 8);   // 512 balanced blocks: n = bx&63, pair = bx>>6
    dim3 block(256);
    hipLaunchKernelGGL(attn_fwd, grid, block, 0, stream, q, k, v, o);
}